// Round 2
// baseline (405.048 us; speedup 1.0000x reference)
//
#include <hip/hip_runtime.h>
#include <hip/hip_bf16.h>

// Problem: nnvit_82042465288319 on MI355X (gfx950).
// B=262144 rows; per row y[5][32]; 2 layers (H=8, HD=4); out = y[0] after layer 1.
//
// Round 1 design:
//  - Inputs are float32 per the reference contract, but a device-side dtype probe
//    (prep kernel) handles bf16 too: both load/store paths, wave-uniform branch.
//  - prep kernel: weights -> fp16 pairs in d_ws, biases/pos_bias -> f32, + dtype flag.
//  - main kernel: 1 thread = 1 batch row. y kept as 80 packed fp16 pairs in regs.
//    Dots via v_dot2_f32_f16 (f32 accum); weights are wave-uniform (SGPR broadcast).
//  - layer 1 computes only token-0 q/attn/o/proj row (output needs only y[0]).
//  - per-thread LDS scratch in [slot][tid] layout (conflict-free, no barriers).

#define BLOCK 128
#define NTOK 5

typedef decltype(__builtin_amdgcn_cvt_pkrtz(0.0f, 0.0f)) half2_t;

__device__ __forceinline__ float bf2f(unsigned short u) {
  union { unsigned int u; float f; } c; c.u = ((unsigned int)u) << 16; return c.f;
}
__device__ __forceinline__ half2_t bfpair2h2(unsigned int u) {
  union { unsigned int u; float f; } lo, hi;
  lo.u = u << 16;
  hi.u = u & 0xffff0000u;
  return __builtin_amdgcn_cvt_pkrtz(lo.f, hi.f);  // exact: bf16 fits fp16 for |x|<65504
}
__device__ __forceinline__ unsigned int h2bits(half2_t v) {
  union { half2_t h; unsigned int u; } c; c.h = v; return c.u;
}
__device__ __forceinline__ half2_t bits2h2(unsigned int u) {
  union { half2_t h; unsigned int u; } c; c.u = u; return c.h;
}
// round-to-nearest-even f32 pair -> packed bf16 pair
__device__ __forceinline__ unsigned int f2bfpair(float a, float b) {
  unsigned int ua = __float_as_uint(a), ub = __float_as_uint(b);
  ua = (ua + 0x7fffu + ((ua >> 16) & 1u)) >> 16;
  ub = (ub + 0x7fffu + ((ub >> 16) & 1u)) & 0xffff0000u;
  return ua | ub;
}

// dtype probe: low 16 bits of each word are a bf16 value (exponent in normal band)
// iff data is bf16; for f32 data they are uniform mantissa bits. 64 samples, 8-sigma.
__device__ __forceinline__ int detect_bf16(const unsigned int* __restrict__ p) {
  int cnt = 0;
#pragma unroll
  for (int i = 0; i < 64; ++i) {
    unsigned int e = (p[i] >> 7) & 0xffu;
    cnt += (e >= 96u && e <= 150u) ? 1 : 0;
  }
  return (cnt >= 40) ? 1 : 0;
}

// 32-wide dot: 16 x v_dot2_f32_f16, f32 accumulator
__device__ __forceinline__ float rowdot16(const half2_t* __restrict__ w,
                                          const half2_t (&yt)[16], float acc) {
#pragma unroll
  for (int i = 0; i < 16; ++i) acc = __builtin_amdgcn_fdot2(yt[i], w[i], acc, false);
  return acc;
}

// ---------------- prep: convert weights into d_ws (single block!) ----------------
// ws layout (bytes):
//   wqkv : uint[3072] @ 0      | wproj: uint[1024] @ 12288 | bqkv: f32[192] @ 16384
//   bproj: f32[64] @ 17152    | pb: f32[400] @ 17408      | flag: int @ 19008
__global__ void prep_kernel(const void* __restrict__ xraw,
                            const void* __restrict__ qkv_w, const void* __restrict__ qkv_b,
                            const void* __restrict__ proj_w, const void* __restrict__ proj_b,
                            const void* __restrict__ pos_b,
                            unsigned int* __restrict__ wqkv, unsigned int* __restrict__ wproj,
                            float* __restrict__ bqkv, float* __restrict__ bproj,
                            float* __restrict__ pb, int* __restrict__ flag) {
  const int t = threadIdx.x;                       // single block of 256
  const int isbf = detect_bf16((const unsigned int*)xraw);  // every thread: same answer
  if (t == 0) *flag = isbf;
  if (isbf) {
    const unsigned short* qw = (const unsigned short*)qkv_w;
    const unsigned short* qb = (const unsigned short*)qkv_b;
    const unsigned short* pw = (const unsigned short*)proj_w;
    const unsigned short* pbb = (const unsigned short*)proj_b;
    const unsigned short* pp = (const unsigned short*)pos_b;
    for (int i = t; i < 3072; i += 256)
      wqkv[i] = h2bits(__builtin_amdgcn_cvt_pkrtz(bf2f(qw[2 * i]), bf2f(qw[2 * i + 1])));
    for (int i = t; i < 1024; i += 256)
      wproj[i] = h2bits(__builtin_amdgcn_cvt_pkrtz(bf2f(pw[2 * i]), bf2f(pw[2 * i + 1])));
    for (int i = t; i < 192; i += 256) bqkv[i] = bf2f(qb[i]);
    for (int i = t; i < 64; i += 256) bproj[i] = bf2f(pbb[i]);
    for (int i = t; i < 400; i += 256) pb[i] = bf2f(pp[i]);
  } else {
    const float* qw = (const float*)qkv_w;
    const float* qb = (const float*)qkv_b;
    const float* pw = (const float*)proj_w;
    const float* pbb = (const float*)proj_b;
    const float* pp = (const float*)pos_b;
    for (int i = t; i < 3072; i += 256)
      wqkv[i] = h2bits(__builtin_amdgcn_cvt_pkrtz(qw[2 * i], qw[2 * i + 1]));
    for (int i = t; i < 1024; i += 256)
      wproj[i] = h2bits(__builtin_amdgcn_cvt_pkrtz(pw[2 * i], pw[2 * i + 1]));
    for (int i = t; i < 192; i += 256) bqkv[i] = qb[i];
    for (int i = t; i < 64; i += 256) bproj[i] = pbb[i];
    for (int i = t; i < 400; i += 256) pb[i] = pp[i];
  }
}

// ---------------- attention block (qkv + softmax + o), NROWS q-rows ----------------
template <int NROWS>
__device__ __forceinline__ void attn_block(const int l, const half2_t (&y)[NTOK][16],
                                           unsigned int* __restrict__ olds, const int tid,
                                           const half2_t* __restrict__ wqkv,
                                           const float* __restrict__ bqkv,
                                           const float* __restrict__ pb) {
#pragma unroll 1  // keep head loop rolled: body fits I-cache once
  for (int h = 0; h < 8; ++h) {
    const half2_t* wq = wqkv + (l * 96 + h * 4) * 16;
    const half2_t* wk = wq + 32 * 16;
    const half2_t* wv = wq + 64 * 16;
    const float* bq = bqkv + l * 96 + h * 4;

    half2_t kp[NTOK][2];
    float vv[NTOK][4];
    half2_t qp[NROWS][2];

#pragma unroll
    for (int t = 0; t < NTOK; ++t) {
      float f0 = rowdot16(wk + 0 * 16, y[t], bq[32 + 0]);
      float f1 = rowdot16(wk + 1 * 16, y[t], bq[32 + 1]);
      float f2 = rowdot16(wk + 2 * 16, y[t], bq[32 + 2]);
      float f3 = rowdot16(wk + 3 * 16, y[t], bq[32 + 3]);
      kp[t][0] = __builtin_amdgcn_cvt_pkrtz(f0, f1);
      kp[t][1] = __builtin_amdgcn_cvt_pkrtz(f2, f3);
#pragma unroll
      for (int j = 0; j < 4; ++j) vv[t][j] = rowdot16(wv + j * 16, y[t], bq[64 + j]);
    }
#pragma unroll
    for (int n = 0; n < NROWS; ++n) {
      float f0 = rowdot16(wq + 0 * 16, y[n], bq[0]);
      float f1 = rowdot16(wq + 1 * 16, y[n], bq[1]);
      float f2 = rowdot16(wq + 2 * 16, y[n], bq[2]);
      float f3 = rowdot16(wq + 3 * 16, y[n], bq[3]);
      qp[n][0] = __builtin_amdgcn_cvt_pkrtz(f0, f1);
      qp[n][1] = __builtin_amdgcn_cvt_pkrtz(f2, f3);
    }

    const float* pbh = pb + (l * 8 + h) * 25;
#pragma unroll
    for (int n = 0; n < NROWS; ++n) {
      float lg[NTOK];
#pragma unroll
      for (int m = 0; m < NTOK; ++m) {
        float d = __builtin_amdgcn_fdot2(qp[n][0], kp[m][0], 0.0f, false);
        d = __builtin_amdgcn_fdot2(qp[n][1], kp[m][1], d, false);
        lg[m] = fmaf(d, 0.5f, pbh[n * 5 + m]);  // scale = HD^-0.5 = 0.5
      }
      float mx = fmaxf(fmaxf(fmaxf(lg[0], lg[1]), fmaxf(lg[2], lg[3])), lg[4]);
      float e[NTOK], s = 0.0f;
#pragma unroll
      for (int m = 0; m < NTOK; ++m) {
        e[m] = __builtin_amdgcn_exp2f((lg[m] - mx) * 1.44269504f);
        s += e[m];
      }
      const float r = __builtin_amdgcn_rcpf(s);  // s >= 1 always
      float o0 = 0.f, o1 = 0.f, o2 = 0.f, o3 = 0.f;
#pragma unroll
      for (int m = 0; m < NTOK; ++m) {
        o0 = fmaf(e[m], vv[m][0], o0);
        o1 = fmaf(e[m], vv[m][1], o1);
        o2 = fmaf(e[m], vv[m][2], o2);
        o3 = fmaf(e[m], vv[m][3], o3);
      }
      olds[(n * 16 + 2 * h + 0) * BLOCK + tid] = h2bits(__builtin_amdgcn_cvt_pkrtz(o0 * r, o1 * r));
      olds[(n * 16 + 2 * h + 1) * BLOCK + tid] = h2bits(__builtin_amdgcn_cvt_pkrtz(o2 * r, o3 * r));
    }
  }
}

// ---------------- main kernel: 1 thread = 1 batch row ----------------
__global__ __launch_bounds__(BLOCK, 2) void vit_kernel(
    const void* __restrict__ x, const void* __restrict__ token,
    const half2_t* __restrict__ wqkv, const half2_t* __restrict__ wproj,
    const float* __restrict__ bqkv, const float* __restrict__ bproj,
    const float* __restrict__ pb, const int* __restrict__ flag,
    void* __restrict__ out) {
  __shared__ unsigned int o_lds[NTOK * 16 * BLOCK];  // 40 KiB per-thread scratch
  const int tid = threadIdx.x;
  const size_t b = (size_t)blockIdx.x * BLOCK + tid;
  const int isbf = *flag;  // wave-uniform

  half2_t y[NTOK][16];  // y[t][i] = channels (2i, 2i+1), packed fp16
  if (isbf) {
    const uint4* tp = (const uint4*)token;
#pragma unroll
    for (int r = 0; r < 4; ++r) {
      uint4 u = tp[r];
      y[0][r * 4 + 0] = bfpair2h2(u.x);
      y[0][r * 4 + 1] = bfpair2h2(u.y);
      y[0][r * 4 + 2] = bfpair2h2(u.z);
      y[0][r * 4 + 3] = bfpair2h2(u.w);
    }
    const uint4* xp = (const uint4*)((const unsigned short*)x + b * 128);
#pragma unroll
    for (int r = 0; r < 16; ++r) {
      uint4 u = xp[r];
      const int t = 1 + (r >> 2), c = (r & 3) * 4;
      y[t][c + 0] = bfpair2h2(u.x);
      y[t][c + 1] = bfpair2h2(u.y);
      y[t][c + 2] = bfpair2h2(u.z);
      y[t][c + 3] = bfpair2h2(u.w);
    }
  } else {
    const float4* tp = (const float4*)token;
#pragma unroll
    for (int r = 0; r < 8; ++r) {
      float4 u = tp[r];
      y[0][r * 2 + 0] = __builtin_amdgcn_cvt_pkrtz(u.x, u.y);
      y[0][r * 2 + 1] = __builtin_amdgcn_cvt_pkrtz(u.z, u.w);
    }
    const float4* xp = (const float4*)((const float*)x + b * 128);
#pragma unroll
    for (int r = 0; r < 32; ++r) {
      float4 u = xp[r];
      const int t = 1 + (r >> 3), c = (r & 7) * 2;
      y[t][c + 0] = __builtin_amdgcn_cvt_pkrtz(u.x, u.y);
      y[t][c + 1] = __builtin_amdgcn_cvt_pkrtz(u.z, u.w);
    }
  }

  // ================= layer 0 (full) =================
  attn_block<NTOK>(0, y, o_lds, tid, wqkv, bqkv, pb);
#pragma unroll
  for (int n = 0; n < NTOK; ++n) {
    half2_t orow[16];
#pragma unroll
    for (int i = 0; i < 16; ++i) orow[i] = bits2h2(o_lds[(n * 16 + i) * BLOCK + tid]);
#pragma unroll 1  // rolled; proj result via LDS to avoid dynamic reg indexing
    for (int jj = 0; jj < 16; ++jj) {
      float p0 = rowdot16(wproj + (2 * jj + 0) * 16, orow, bproj[2 * jj + 0]);
      float p1 = rowdot16(wproj + (2 * jj + 1) * 16, orow, bproj[2 * jj + 1]);
      o_lds[(n * 16 + jj) * BLOCK + tid] = h2bits(__builtin_amdgcn_cvt_pkrtz(p0, p1));
    }
#pragma unroll
    for (int i = 0; i < 16; ++i) {  // residual: y += proj(o)
      half2_t pv = bits2h2(o_lds[(n * 16 + i) * BLOCK + tid]);
      float a0 = (float)y[n][i].x + (float)pv.x;
      float a1 = (float)y[n][i].y + (float)pv.y;
      y[n][i] = __builtin_amdgcn_cvt_pkrtz(a0, a1);
    }
  }

  // ================= layer 1 (token-0 row only) =================
  attn_block<1>(1, y, o_lds, tid, wqkv, bqkv, pb);
  {
    half2_t orow[16];
#pragma unroll
    for (int i = 0; i < 16; ++i) orow[i] = bits2h2(o_lds[i * BLOCK + tid]);
    float rf[32];
#pragma unroll  // fully unrolled: rf[] must stay in registers
    for (int jj = 0; jj < 16; ++jj) {
      float p0 = rowdot16(wproj + (32 + 2 * jj + 0) * 16, orow, bproj[32 + 2 * jj + 0]);
      float p1 = rowdot16(wproj + (32 + 2 * jj + 1) * 16, orow, bproj[32 + 2 * jj + 1]);
      rf[2 * jj + 0] = (float)y[0][jj].x + p0;
      rf[2 * jj + 1] = (float)y[0][jj].y + p1;
    }
    if (isbf) {
      unsigned int res[16];
#pragma unroll
      for (int jj = 0; jj < 16; ++jj) res[jj] = f2bfpair(rf[2 * jj], rf[2 * jj + 1]);
      uint4* op = (uint4*)((unsigned short*)out + b * 32);
#pragma unroll
      for (int r = 0; r < 4; ++r)
        op[r] = make_uint4(res[r * 4], res[r * 4 + 1], res[r * 4 + 2], res[r * 4 + 3]);
    } else {
      float4* op = (float4*)((float*)out + b * 32);
#pragma unroll
      for (int r = 0; r < 8; ++r)
        op[r] = make_float4(rf[r * 4], rf[r * 4 + 1], rf[r * 4 + 2], rf[r * 4 + 3]);
    }
  }
}

extern "C" void kernel_launch(void* const* d_in, const int* in_sizes, int n_in,
                              void* d_out, int out_size, void* d_ws, size_t ws_size,
                              hipStream_t stream) {
  const void* x      = d_in[0];
  const void* token  = d_in[1];
  const void* qkv_w  = d_in[2];
  const void* qkv_b  = d_in[3];
  const void* proj_w = d_in[4];
  const void* proj_b = d_in[5];
  const void* pos_b  = d_in[6];

  char* ws = (char*)d_ws;
  unsigned int* wqkv  = (unsigned int*)(ws + 0);      // 12288 B
  unsigned int* wproj = (unsigned int*)(ws + 12288);  //  4096 B
  float* bqkv  = (float*)(ws + 16384);                //   768 B
  float* bproj = (float*)(ws + 17152);                //   256 B
  float* pb    = (float*)(ws + 17408);                //  1600 B
  int*   flag  = (int*)(ws + 19008);                  //     4 B

  prep_kernel<<<1, 256, 0, stream>>>(x, qkv_w, qkv_b, proj_w, proj_b, pos_b,
                                     wqkv, wproj, bqkv, bproj, pb, flag);

  const int nrows = in_sizes[0] / 128;     // 262144 batch rows
  const int grid = nrows / BLOCK;          // 2048 blocks of 128
  vit_kernel<<<grid, BLOCK, 0, stream>>>(x, token,
                                         (const half2_t*)wqkv, (const half2_t*)wproj,
                                         bqkv, bproj, pb, flag, d_out);
}

// Round 3
// 240.004 us; speedup vs baseline: 1.6877x; 1.6877x over previous
//
#include <hip/hip_runtime.h>
#include <hip/hip_bf16.h>

// nnvit_82042465288319 on MI355X (gfx950). B=262144 rows; y[5][32]; 2 layers
// (H=8, HD=4); out = y[0] after layer 1. Inputs f32 (dtype probe keeps a bf16
// path for safety).
//
// Round 3 design (MFMA):
//  - wave = 16 batch elements; lane (quad=lane>>4, nl=lane&15).
//  - qkv/proj GEMMs via mfma_f32_16x16x32_f16: A = weight tile (m = out-ch,
//    lane&15 on input), B = y^T (n = batch, lane&15), K = 32 exactly.
//    C/D: col(batch)=lane&15, row(out-ch)=quad*4+reg [m89 layout].
//  - After qkv, lane (quad,nl) holds full q,k,v for heads {quad, quad+4} of
//    batch nl -> attention is 100% per-lane (no LDS, no shuffles).
//  - o -> proj-B operand and projC -> y layout need an 8-shuffle regroup
//    (lane holds ch-groups {quad,quad+4}, needs {2*quad, 2*quad+1}).
//  - Layer 1: q-tiles only for token 0; attention row 0; proj token 0 only.
//  - LDS = 0. Occupancy VGPR-bound (~2 waves/SIMD), high-ILP straight line.

#define NTOK 5

typedef decltype(__builtin_amdgcn_cvt_pkrtz(0.0f, 0.0f)) half2_t;
using half8_t = __attribute__((ext_vector_type(8))) _Float16;
using f32x4 = __attribute__((ext_vector_type(4))) float;

union H2 { half2_t h; unsigned int u; };
union H8 { half8_t h; uint4 u4; unsigned int u[4]; };

__device__ __forceinline__ half2_t u2h(unsigned int x) { H2 c; c.u = x; return c.h; }
__device__ __forceinline__ unsigned int h2u(half2_t h) { H2 c; c.h = h; return c.u; }
__device__ __forceinline__ unsigned int pk(float a, float b) {
  return h2u(__builtin_amdgcn_cvt_pkrtz(a, b));
}
__device__ __forceinline__ float bf2f(unsigned short u) {
  union { unsigned int u; float f; } c; c.u = ((unsigned int)u) << 16; return c.f;
}
__device__ __forceinline__ half2_t bfpair2h2(unsigned int u) {
  union { unsigned int u; float f; } lo, hi;
  lo.u = u << 16;
  hi.u = u & 0xffff0000u;
  return __builtin_amdgcn_cvt_pkrtz(lo.f, hi.f);  // exact: bf16 fits fp16 range here
}
// round-to-nearest-even f32 pair -> packed bf16 pair
__device__ __forceinline__ unsigned int f2bfpair(float a, float b) {
  unsigned int ua = __float_as_uint(a), ub = __float_as_uint(b);
  ua = (ua + 0x7fffu + ((ua >> 16) & 1u)) >> 16;
  ub = (ub + 0x7fffu + ((ub >> 16) & 1u)) & 0xffff0000u;
  return ua | ub;
}

// dtype probe: low 16 bits of each word form a normal-band bf16 exponent iff bf16
__device__ __forceinline__ int detect_bf16(const unsigned int* __restrict__ p) {
  int cnt = 0;
#pragma unroll
  for (int i = 0; i < 64; ++i) {
    unsigned int e = (p[i] >> 7) & 0xffu;
    cnt += (e >= 96u && e <= 150u) ? 1 : 0;
  }
  return (cnt >= 40) ? 1 : 0;
}

// ---------------- prep: weights -> fp16 row-major, biases/pos_bias -> f32 ----------------
// ws: wqkv u32[3072]@0 | wproj u32[1024]@12288 | bqkv f32[192]@16384
//     bproj f32[64]@17152 | pb f32[400]@17408 | flag int@19008
__global__ void prep_kernel(const void* __restrict__ xraw,
                            const void* __restrict__ qkv_w, const void* __restrict__ qkv_b,
                            const void* __restrict__ proj_w, const void* __restrict__ proj_b,
                            const void* __restrict__ pos_b,
                            unsigned int* __restrict__ wqkv, unsigned int* __restrict__ wproj,
                            float* __restrict__ bqkv, float* __restrict__ bproj,
                            float* __restrict__ pb, int* __restrict__ flag) {
  const int t = threadIdx.x;  // single block of 256
  const int isbf = detect_bf16((const unsigned int*)xraw);
  if (t == 0) *flag = isbf;
  if (isbf) {
    const unsigned short* qw = (const unsigned short*)qkv_w;
    const unsigned short* qb = (const unsigned short*)qkv_b;
    const unsigned short* pw = (const unsigned short*)proj_w;
    const unsigned short* pbb = (const unsigned short*)proj_b;
    const unsigned short* pp = (const unsigned short*)pos_b;
    for (int i = t; i < 3072; i += 256)
      wqkv[i] = h2u(__builtin_amdgcn_cvt_pkrtz(bf2f(qw[2 * i]), bf2f(qw[2 * i + 1])));
    for (int i = t; i < 1024; i += 256)
      wproj[i] = h2u(__builtin_amdgcn_cvt_pkrtz(bf2f(pw[2 * i]), bf2f(pw[2 * i + 1])));
    for (int i = t; i < 192; i += 256) bqkv[i] = bf2f(qb[i]);
    for (int i = t; i < 64; i += 256) bproj[i] = bf2f(pbb[i]);
    for (int i = t; i < 400; i += 256) pb[i] = bf2f(pp[i]);
  } else {
    const float* qw = (const float*)qkv_w;
    const float* qb = (const float*)qkv_b;
    const float* pw = (const float*)proj_w;
    const float* pbb = (const float*)proj_b;
    const float* pp = (const float*)pos_b;
    for (int i = t; i < 3072; i += 256)
      wqkv[i] = h2u(__builtin_amdgcn_cvt_pkrtz(qw[2 * i], qw[2 * i + 1]));
    for (int i = t; i < 1024; i += 256)
      wproj[i] = h2u(__builtin_amdgcn_cvt_pkrtz(pw[2 * i], pw[2 * i + 1]));
    for (int i = t; i < 192; i += 256) bqkv[i] = qb[i];
    for (int i = t; i < 64; i += 256) bproj[i] = pbb[i];
    for (int i = t; i < 400; i += 256) pb[i] = pp[i];
  }
}

// A-fragment load: lane holds W[row][quad*8 .. quad*8+7] (8 contiguous fp16 = 16B)
__device__ __forceinline__ half8_t ldfrag(const uint4* __restrict__ w, int row, int quad) {
  H8 c; c.u4 = w[row * 4 + quad]; return c.h;
}
__device__ __forceinline__ half8_t mk8(const unsigned int (&d)[4]) {
  H8 c; c.u[0] = d[0]; c.u[1] = d[1]; c.u[2] = d[2]; c.u[3] = d[3]; return c.h;
}

// qkv GEMM for one token: 6 (or 4) MFMAs; C packed to fp16 dword pairs.
// tile 0/1 = q heads {quad, quad+4}; 2/3 = k; 4/5 = v.
template <int TMIN>
__device__ __forceinline__ void qkv_token(const half8_t (&wa)[6], const f32x4 (&bias)[6],
                                          half8_t yb, unsigned int (&outdw)[6][2]) {
#pragma unroll
  for (int tile = TMIN; tile < 6; ++tile) {
    f32x4 acc = __builtin_amdgcn_mfma_f32_16x16x32_f16(wa[tile], yb, bias[tile], 0, 0, 0);
    outdw[tile][0] = pk(acc[0], acc[1]);
    outdw[tile][1] = pk(acc[2], acc[3]);
  }
}

// per-lane attention for NR q-rows; slot s -> head quad+4s
template <int NR>
__device__ __forceinline__ void attention(const unsigned int (&dw)[NTOK][6][2],
                                          const float* __restrict__ pbl, int quad,
                                          unsigned int (&od)[2][NR][2]) {
#pragma unroll
  for (int s = 0; s < 2; ++s) {
    const float* pbh = pbl + (quad + 4 * s) * 25;
    float vf[NTOK][4];
#pragma unroll
    for (int m = 0; m < NTOK; ++m) {
      half2_t v0 = u2h(dw[m][4 + s][0]), v1 = u2h(dw[m][4 + s][1]);
      vf[m][0] = (float)v0.x; vf[m][1] = (float)v0.y;
      vf[m][2] = (float)v1.x; vf[m][3] = (float)v1.y;
    }
#pragma unroll
    for (int n = 0; n < NR; ++n) {
      float lg[NTOK];
#pragma unroll
      for (int m = 0; m < NTOK; ++m) {
        float d = __builtin_amdgcn_fdot2(u2h(dw[n][0 + s][0]), u2h(dw[m][2 + s][0]), 0.0f, false);
        d = __builtin_amdgcn_fdot2(u2h(dw[n][0 + s][1]), u2h(dw[m][2 + s][1]), d, false);
        lg[m] = fmaf(d, 0.5f, pbh[n * 5 + m]);  // scale = HD^-0.5 = 0.5
      }
      float mx = fmaxf(fmaxf(fmaxf(lg[0], lg[1]), fmaxf(lg[2], lg[3])), lg[4]);
      float e[NTOK], ssum = 0.0f;
#pragma unroll
      for (int m = 0; m < NTOK; ++m) {
        e[m] = __builtin_amdgcn_exp2f((lg[m] - mx) * 1.44269504f);
        ssum += e[m];
      }
      const float r = __builtin_amdgcn_rcpf(ssum);
      float o0 = 0.f, o1 = 0.f, o2 = 0.f, o3 = 0.f;
#pragma unroll
      for (int m = 0; m < NTOK; ++m) {
        o0 = fmaf(e[m], vf[m][0], o0); o1 = fmaf(e[m], vf[m][1], o1);
        o2 = fmaf(e[m], vf[m][2], o2); o3 = fmaf(e[m], vf[m][3], o3);
      }
      od[s][n][0] = pk(o0 * r, o1 * r);
      od[s][n][1] = pk(o2 * r, o3 * r);
    }
  }
}

// lane holds ch-groups {quad, quad+4} (2 dwords each); target: groups {2q, 2q+1}
__device__ __forceinline__ void regroup(int quad, int nl,
                                        unsigned int lo0, unsigned int lo1,
                                        unsigned int hi0, unsigned int hi1,
                                        unsigned int (&o)[4]) {
  const int sA = ((2 * quad) & 3) * 16 + nl;
  const int sB = ((2 * quad + 1) & 3) * 16 + nl;
  const unsigned int a0 = __shfl((int)lo0, sA, 64), a1 = __shfl((int)lo1, sA, 64);
  const unsigned int a2 = __shfl((int)hi0, sA, 64), a3 = __shfl((int)hi1, sA, 64);
  const unsigned int b0 = __shfl((int)lo0, sB, 64), b1 = __shfl((int)lo1, sB, 64);
  const unsigned int b2 = __shfl((int)hi0, sB, 64), b3 = __shfl((int)hi1, sB, 64);
  const bool hi = quad >= 2;  // groups 2q,2q+1 live in source's hi slot iff q>=2
  o[0] = hi ? a2 : a0; o[1] = hi ? a3 : a1;
  o[2] = hi ? b2 : b0; o[3] = hi ? b3 : b1;
}

// ---------------- main kernel: 1 wave = 16 batch rows ----------------
__global__ __launch_bounds__(256, 2) void vit_kernel(
    const void* __restrict__ x, const void* __restrict__ token,
    const unsigned int* __restrict__ wqkv, const unsigned int* __restrict__ wproj,
    const float* __restrict__ bqkv, const float* __restrict__ bproj,
    const float* __restrict__ pb, const int* __restrict__ flag,
    void* __restrict__ out) {
  const int tid = threadIdx.x;
  const int wave = tid >> 6, lane = tid & 63;
  const int quad = lane >> 4, nl = lane & 15;
  const size_t b = (size_t)blockIdx.x * 64 + wave * 16 + nl;
  const int isbf = *flag;  // wave-uniform

  // y in B-operand layout: yd[t][j] = fp16 pair (ch quad*8+2j, quad*8+2j+1) of batch b
  unsigned int yd[NTOK][4];
  if (isbf) {
    const uint4 tk = *(const uint4*)((const unsigned short*)token + quad * 8);
    yd[0][0] = h2u(bfpair2h2(tk.x)); yd[0][1] = h2u(bfpair2h2(tk.y));
    yd[0][2] = h2u(bfpair2h2(tk.z)); yd[0][3] = h2u(bfpair2h2(tk.w));
#pragma unroll
    for (int t = 1; t < NTOK; ++t) {
      const uint4 u = *(const uint4*)((const unsigned short*)x + b * 128 + (t - 1) * 32 + quad * 8);
      yd[t][0] = h2u(bfpair2h2(u.x)); yd[t][1] = h2u(bfpair2h2(u.y));
      yd[t][2] = h2u(bfpair2h2(u.z)); yd[t][3] = h2u(bfpair2h2(u.w));
    }
  } else {
    const float4* tp = (const float4*)token;
    float4 a0 = tp[quad * 2], a1 = tp[quad * 2 + 1];
    yd[0][0] = pk(a0.x, a0.y); yd[0][1] = pk(a0.z, a0.w);
    yd[0][2] = pk(a1.x, a1.y); yd[0][3] = pk(a1.z, a1.w);
#pragma unroll
    for (int t = 1; t < NTOK; ++t) {
      const float4* xp = (const float4*)((const float*)x + b * 128 + (t - 1) * 32 + quad * 8);
      float4 u0 = xp[0], u1 = xp[1];
      yd[t][0] = pk(u0.x, u0.y); yd[t][1] = pk(u0.z, u0.w);
      yd[t][2] = pk(u1.x, u1.y); yd[t][3] = pk(u1.z, u1.w);
    }
  }

  const uint4* wq4 = (const uint4*)wqkv;
  const uint4* wp4 = (const uint4*)wproj;

  // ===================== layer 0 =====================
  {
    half8_t wa[6]; f32x4 bias[6];
#pragma unroll
    for (int tile = 0; tile < 6; ++tile) {
      wa[tile] = ldfrag(wq4, tile * 16 + nl, quad);
      bias[tile] = *(const f32x4*)(bqkv + tile * 16 + quad * 4);
    }
    unsigned int dw[NTOK][6][2];
#pragma unroll
    for (int t = 0; t < NTOK; ++t) qkv_token<0>(wa, bias, mk8(yd[t]), dw[t]);

    unsigned int od[2][NTOK][2];
    attention<NTOK>(dw, pb, quad, od);

    half8_t wp[2]; f32x4 bp[2];
#pragma unroll
    for (int tile = 0; tile < 2; ++tile) {
      wp[tile] = ldfrag(wp4, tile * 16 + nl, quad);
      bp[tile] = *(const f32x4*)(bproj + tile * 16 + quad * 4);
    }
#pragma unroll
    for (int t = 0; t < NTOK; ++t) {
      unsigned int bfd[4];
      regroup(quad, nl, od[0][t][0], od[0][t][1], od[1][t][0], od[1][t][1], bfd);
      f32x4 p0 = __builtin_amdgcn_mfma_f32_16x16x32_f16(wp[0], mk8(bfd), bp[0], 0, 0, 0);
      f32x4 p1 = __builtin_amdgcn_mfma_f32_16x16x32_f16(wp[1], mk8(bfd), bp[1], 0, 0, 0);
      unsigned int pr[4];
      regroup(quad, nl, pk(p0[0], p0[1]), pk(p0[2], p0[3]), pk(p1[0], p1[1]), pk(p1[2], p1[3]), pr);
#pragma unroll
      for (int j = 0; j < 4; ++j) yd[t][j] = h2u(u2h(yd[t][j]) + u2h(pr[j]));  // residual
    }
  }

  // ===================== layer 1 (token-0 output only) =====================
  {
    half8_t wa[6]; f32x4 bias[6];
#pragma unroll
    for (int tile = 0; tile < 6; ++tile) {
      wa[tile] = ldfrag(wq4, 96 + tile * 16 + nl, quad);
      bias[tile] = *(const f32x4*)(bqkv + 96 + tile * 16 + quad * 4);
    }
    unsigned int dw[NTOK][6][2];
    qkv_token<0>(wa, bias, mk8(yd[0]), dw[0]);  // token 0: q,k,v
#pragma unroll
    for (int t = 1; t < NTOK; ++t) qkv_token<2>(wa, bias, mk8(yd[t]), dw[t]);  // k,v only

    unsigned int od[2][1][2];
    attention<1>(dw, pb + 200, quad, od);

    half8_t wp[2]; f32x4 bp[2];
#pragma unroll
    for (int tile = 0; tile < 2; ++tile) {
      wp[tile] = ldfrag(wp4, 32 + tile * 16 + nl, quad);
      bp[tile] = *(const f32x4*)(bproj + 32 + tile * 16 + quad * 4);
    }
    unsigned int bfd[4];
    regroup(quad, nl, od[0][0][0], od[0][0][1], od[1][0][0], od[1][0][1], bfd);
    f32x4 p0 = __builtin_amdgcn_mfma_f32_16x16x32_f16(wp[0], mk8(bfd), bp[0], 0, 0, 0);
    f32x4 p1 = __builtin_amdgcn_mfma_f32_16x16x32_f16(wp[1], mk8(bfd), bp[1], 0, 0, 0);

    // f32-exact regroup of proj output into y layout (chs quad*8..+7)
    unsigned int t0[4], t1[4];
    regroup(quad, nl, __float_as_uint(p0[0]), __float_as_uint(p0[1]),
            __float_as_uint(p1[0]), __float_as_uint(p1[1]), t0);
    regroup(quad, nl, __float_as_uint(p0[2]), __float_as_uint(p0[3]),
            __float_as_uint(p1[2]), __float_as_uint(p1[3]), t1);
    float pf[8] = {__uint_as_float(t0[0]), __uint_as_float(t0[1]),
                   __uint_as_float(t1[0]), __uint_as_float(t1[1]),
                   __uint_as_float(t0[2]), __uint_as_float(t0[3]),
                   __uint_as_float(t1[2]), __uint_as_float(t1[3])};
    float f[8];
#pragma unroll
    for (int j = 0; j < 4; ++j) {
      half2_t yv = u2h(yd[0][j]);
      f[2 * j + 0] = (float)yv.x + pf[2 * j + 0];
      f[2 * j + 1] = (float)yv.y + pf[2 * j + 1];
    }
    if (isbf) {
      uint4 r = make_uint4(f2bfpair(f[0], f[1]), f2bfpair(f[2], f[3]),
                           f2bfpair(f[4], f[5]), f2bfpair(f[6], f[7]));
      *(uint4*)((unsigned short*)out + b * 32 + quad * 8) = r;
    } else {
      float4* op = (float4*)((float*)out + b * 32 + quad * 8);
      op[0] = make_float4(f[0], f[1], f[2], f[3]);
      op[1] = make_float4(f[4], f[5], f[6], f[7]);
    }
  }
}

extern "C" void kernel_launch(void* const* d_in, const int* in_sizes, int n_in,
                              void* d_out, int out_size, void* d_ws, size_t ws_size,
                              hipStream_t stream) {
  const void* x      = d_in[0];
  const void* token  = d_in[1];
  const void* qkv_w  = d_in[2];
  const void* qkv_b  = d_in[3];
  const void* proj_w = d_in[4];
  const void* proj_b = d_in[5];
  const void* pos_b  = d_in[6];

  char* ws = (char*)d_ws;
  unsigned int* wqkv  = (unsigned int*)(ws + 0);
  unsigned int* wproj = (unsigned int*)(ws + 12288);
  float* bqkv  = (float*)(ws + 16384);
  float* bproj = (float*)(ws + 17152);
  float* pb    = (float*)(ws + 17408);
  int*   flag  = (int*)(ws + 19008);

  prep_kernel<<<1, 256, 0, stream>>>(x, qkv_w, qkv_b, proj_w, proj_b, pos_b,
                                     wqkv, wproj, bqkv, bproj, pb, flag);

  const int nrows = in_sizes[0] / 128;  // 262144 batch rows
  const int grid = nrows / 64;          // 64 rows per 256-thread block (4 waves x 16)
  vit_kernel<<<grid, 256, 0, stream>>>(x, token, wqkv, wproj, bqkv, bproj, pb, flag, d_out);
}